// Round 9
// baseline (1330.723 us; speedup 1.0000x reference)
//
#include <hip/hip_runtime.h>
#include <hip/hip_fp16.h>
#include <math.h>

#define EDGES 120000
#define NN    30000
#define NCH   118        // ceil(30000/256) for CSR-build scans
#define CHUNKS 118       // ceil(30000/256) node chunks per plane
#define T1SLOT 15360000  // halfs per slot (NN*64*8)

__device__ __forceinline__ float sigmoidf_(float x) { return 1.f / (1.f + __expf(-x)); }

typedef float f4raw __attribute__((ext_vector_type(4)));
union F4H8 { float4 v; f4raw r; __half h[8]; };
union F2H4 { float2 v; __half h[4]; };

__device__ __forceinline__ void unpack8(float4 v, float* f) {
  F4H8 u; u.v = v;
#pragma unroll
  for (int i = 0; i < 8; ++i) f[i] = __half2float(u.h[i]);
}
__device__ __forceinline__ float4 pack8(const float* f) {
  F4H8 u;
#pragma unroll
  for (int i = 0; i < 8; ++i) u.h[i] = __float2half(f[i]);
  return u.v;
}
__device__ __forceinline__ void unpack4(float2 v, float* f) {
  F2H4 u; u.v = v;
#pragma unroll
  for (int i = 0; i < 4; ++i) f[i] = __half2float(u.h[i]);
}
__device__ __forceinline__ float2 pack4(const float* f) {
  F2H4 u;
#pragma unroll
  for (int i = 0; i < 4; ++i) u.h[i] = __float2half(f[i]);
  return u.v;
}
__device__ __forceinline__ void nt_store4(float4* p, float4 v) {
  F4H8 u; u.v = v;
  __builtin_nontemporal_store(u.r, reinterpret_cast<f4raw*>(p));
}
__device__ __forceinline__ float4 nt_load4(const float4* p) {
  F4H8 u; u.r = __builtin_nontemporal_load(reinterpret_cast<const f4raw*>(p));
  return u.v;
}

// CSR slot layout (ints): rowptr[30016] | pack int2[120000] (src, norm-bits)
#define CSR_STRIDE 270016
#define CSR_RP(base, l)   ((base) + (size_t)(l) * CSR_STRIDE)
#define CSR_PK(base, l)   ((const int2*)((base) + (size_t)(l) * CSR_STRIDE + 30016))
#define CSR_PKW(base, l)  ((int2*)((base) + (size_t)(l) * CSR_STRIDE + 30016))

// ---------------- CSR build ----------------
__global__ void count_all_kernel(const int* __restrict__ hg, const int* __restrict__ tg,
                                 int* __restrict__ degO, int* __restrict__ degI) {
  int tid = blockIdx.x * blockDim.x + threadIdx.x;
  if (tid >= 4 * EDGES) return;
  int l = tid / EDGES, j = tid - l * EDGES;
  const int* G = (l < 2) ? hg : tg;
  const int* src = G + (size_t)(l & 1) * 2 * EDGES;
  const int* dst = src + EDGES;
  atomicAdd(&degO[l * NN + src[j]], 1);
  atomicAdd(&degI[l * NN + dst[j]], 1);
}

__global__ __launch_bounds__(256) void scan1_kernel(const int* __restrict__ degI,
                                                    int* __restrict__ csrBase,
                                                    int* __restrict__ partials) {
  int l = blockIdx.x / NCH, ch = blockIdx.x - l * NCH;
  int tid = threadIdx.x;
  int i = ch * 256 + tid;
  __shared__ int buf[256];
  int v = (i < NN) ? degI[l * NN + i] : 0;
  buf[tid] = v;
  __syncthreads();
  for (int off = 1; off < 256; off <<= 1) {
    int t = (tid >= off) ? buf[tid - off] : 0;
    __syncthreads();
    buf[tid] += t;
    __syncthreads();
  }
  int* rp = CSR_RP(csrBase, l);
  if (i < NN) rp[i + 1] = buf[tid];
  if (tid == 255) partials[l * NCH + ch] = buf[255];
}

__global__ __launch_bounds__(128) void scan2_kernel(int* __restrict__ partials) {
  __shared__ int buf[128];
  int tid = threadIdx.x;
  for (int l = 0; l < 4; ++l) {
    int v = (tid < NCH) ? partials[l * NCH + tid] : 0;
    buf[tid] = v;
    __syncthreads();
    for (int off = 1; off < 128; off <<= 1) {
      int t = (tid >= off) ? buf[tid - off] : 0;
      __syncthreads();
      buf[tid] += t;
      __syncthreads();
    }
    if (tid < NCH) partials[l * NCH + tid] = buf[tid] - v;  // exclusive
    __syncthreads();
  }
}

__global__ __launch_bounds__(256) void fixup_kernel(int* __restrict__ csrBase,
                                                    int* __restrict__ cursor,
                                                    const int* __restrict__ partials) {
  int l = blockIdx.x / NCH, ch = blockIdx.x - l * NCH;
  int i = ch * 256 + threadIdx.x;
  int* rp = CSR_RP(csrBase, l);
  int off = partials[l * NCH + ch];
  if (i < NN) {
    int val = rp[i + 1] + off;
    rp[i + 1] = val;
    if (i + 1 < NN) cursor[l * NN + i + 1] = val;
  }
  if (i == 0) { rp[0] = 0; cursor[l * NN] = 0; }
}

__global__ void fill_all_kernel(const int* __restrict__ hg, const int* __restrict__ tg,
                                const int* __restrict__ degO, const int* __restrict__ degI,
                                int* __restrict__ cursor, int* __restrict__ csrBase) {
  int tid = blockIdx.x * blockDim.x + threadIdx.x;
  if (tid >= 4 * EDGES) return;
  int l = tid / EDGES, j = tid - l * EDGES;
  const int* G = (l < 2) ? hg : tg;
  const int* src = G + (size_t)(l & 1) * 2 * EDGES;
  const int* dst = src + EDGES;
  int s = src[j], d = dst[j];
  int doo = degO[l * NN + s]; if (doo < 1) doo = 1;
  int dii = degI[l * NN + d]; if (dii < 1) dii = 1;
  float nm = rsqrtf((float)doo) * rsqrtf((float)dii);
  int p = atomicAdd(&cursor[l * NN + d], 1);
  CSR_PKW(csrBase, l)[p] = make_int2(s, __float_as_int(nm));
}

// ---------------- block1 temporal GLU conv: x[B,N,6,1] -> X1p planes [g=batch][n][q=tap][8ch] fp16 ----
__global__ __launch_bounds__(256) void glu1_kernel(const float* __restrict__ x, const float* __restrict__ w,
                                                   const float* __restrict__ b, __half* __restrict__ X1p) {
  int tid = blockIdx.x * 256 + threadIdx.x;   // tid = (g*NN + n)*4 + q, 1.92M threads
  int q = tid & 3;
  int gn = tid >> 2;
  int g = gn / NN, n = gn - g * NN;
  const float* xb = x + ((long)g * NN + n) * 6;
  float x0 = xb[q], x1 = xb[q + 1], x2 = xb[q + 2];
  float o[8];
#pragma unroll
  for (int c = 0; c < 8; ++c) {
    float p = w[c * 3 + 0] * x0 + w[c * 3 + 1] * x1 + w[c * 3 + 2] * x2 + b[c];
    float qq = w[(c + 8) * 3 + 0] * x0 + w[(c + 8) * 3 + 1] * x1 + w[(c + 8) * 3 + 2] * x2 + b[c + 8];
    float al = (c == 0) ? x2 : 0.f;
    o[c] = (p + al) * sigmoidf_(qq);
  }
  reinterpret_cast<float4*>(X1p)[tid] = pack8(o);
}

// ---------------- block1 pull, plane-major, XCD-pinned: T1p[l][g][n] = -sum norm * X1p[g][src] ----
__global__ __launch_bounds__(256) void pull1_kernel(const int* __restrict__ csrBase,
                                                    const __half* __restrict__ X1p,
                                                    __half* __restrict__ T1p) {
  int xcd = blockIdx.x & 7, bslot = blockIdx.x >> 3;   // 2048 blocks
  for (int it = bslot; it < 2 * 4 * CHUNKS; it += 256) {
    int chunk = it % CHUNKS;
    int li = it / CHUNKS;
    int l = li & 3, gl = li >> 2;
    int g = gl * 8 + xcd;
    int n = chunk * 256 + threadIdx.x;
    if (n >= NN) continue;
    const int* rp = CSR_RP(csrBase, l);
    const int2* pk = CSR_PK(csrBase, l);
    const float4* Xp = reinterpret_cast<const float4*>(X1p) + (size_t)g * NN * 4;
    float acc[32];
#pragma unroll
    for (int i = 0; i < 32; ++i) acc[i] = 0.f;
    int e = rp[n], end = rp[n + 1];
    for (; e + 2 <= end; e += 2) {
      int2 p0 = pk[e], p1 = pk[e + 1];
      const float4* r0 = Xp + (size_t)p0.x * 4;
      const float4* r1 = Xp + (size_t)p1.x * 4;
      float4 a0 = r0[0], a1 = r0[1], a2 = r0[2], a3 = r0[3];
      float4 b0 = r1[0], b1 = r1[1], b2 = r1[2], b3 = r1[3];
      float n0 = __int_as_float(p0.y), n1 = __int_as_float(p1.y);
      float f[8];
      unpack8(a0, f);
#pragma unroll
      for (int i = 0; i < 8; ++i) acc[i] -= n0 * f[i];
      unpack8(a1, f);
#pragma unroll
      for (int i = 0; i < 8; ++i) acc[8 + i] -= n0 * f[i];
      unpack8(a2, f);
#pragma unroll
      for (int i = 0; i < 8; ++i) acc[16 + i] -= n0 * f[i];
      unpack8(a3, f);
#pragma unroll
      for (int i = 0; i < 8; ++i) acc[24 + i] -= n0 * f[i];
      unpack8(b0, f);
#pragma unroll
      for (int i = 0; i < 8; ++i) acc[i] -= n1 * f[i];
      unpack8(b1, f);
#pragma unroll
      for (int i = 0; i < 8; ++i) acc[8 + i] -= n1 * f[i];
      unpack8(b2, f);
#pragma unroll
      for (int i = 0; i < 8; ++i) acc[16 + i] -= n1 * f[i];
      unpack8(b3, f);
#pragma unroll
      for (int i = 0; i < 8; ++i) acc[24 + i] -= n1 * f[i];
    }
    for (; e < end; ++e) {
      int2 p = pk[e];
      const float4* r0 = Xp + (size_t)p.x * 4;
      float nm = __int_as_float(p.y);
      float f[8];
#pragma unroll
      for (int rqi = 0; rqi < 4; ++rqi) {
        unpack8(r0[rqi], f);
#pragma unroll
        for (int i = 0; i < 8; ++i) acc[rqi * 8 + i] -= nm * f[i];
      }
    }
    float4* dst = reinterpret_cast<float4*>(T1p) + ((size_t)(l * 16 + g) * NN + n) * 4;
    nt_store4(dst + 0, pack8(acc));
    nt_store4(dst + 1, pack8(acc + 8));
    nt_store4(dst + 2, pack8(acc + 16));
    nt_store4(dst + 3, pack8(acc + 24));
  }
}

// ---------------- block1 Cheb partial, plane-major, XCD-pinned ----------------
// P1[l][g][n] = X*(W0-W2) + T1own*W1 + gather_l(T1)*(-2W2) + bias
__global__ __launch_bounds__(256) void cheb1_kernel(const int* __restrict__ csrBase,
    const __half* __restrict__ X1p, const __half* __restrict__ T1p,
    const float* __restrict__ Whg, const float* __restrict__ bhg,
    const float* __restrict__ Wtg, const float* __restrict__ btg,
    __half* __restrict__ P1) {
  __shared__ float wx[64], w1[64], w2[64], bs[8];
  int xcd = blockIdx.x & 7, bslot = blockIdx.x >> 3;   // 2048 blocks
  for (int it = bslot; it < 2 * 4 * CHUNKS; it += 256) {
    int chunk = it % CHUNKS;
    int li = it / CHUNKS;
    int l = li & 3, gl = li >> 2;
    int g = gl * 8 + xcd;
    __syncthreads();
    {
      int grf = l >> 1, et = l & 1;
      const float* W = (grf ? Wtg : Whg) + et * 3 * 64;
      const float* bias = (grf ? btg : bhg) + et * 8;
      for (int i = threadIdx.x; i < 64; i += 256) {
        float w0v = W[i], w1v = W[64 + i], w2v = W[128 + i];
        wx[i] = w0v - w2v; w1[i] = w1v; w2[i] = -2.f * w2v;
      }
      if (threadIdx.x < 8) bs[threadIdx.x] = bias[threadIdx.x];
    }
    __syncthreads();
    int n = chunk * 256 + threadIdx.x;
    if (n >= NN) continue;
    const int* rp = CSR_RP(csrBase, l);
    const int2* pk = CSR_PK(csrBase, l);
    const float4* Tp = reinterpret_cast<const float4*>(T1p) + (size_t)(l * 16 + g) * NN * 4;
    float acc[32];
#pragma unroll
    for (int i = 0; i < 32; ++i) acc[i] = 0.f;
    int e = rp[n], end = rp[n + 1];
    for (; e + 2 <= end; e += 2) {
      int2 p0 = pk[e], p1 = pk[e + 1];
      const float4* r0 = Tp + (size_t)p0.x * 4;
      const float4* r1 = Tp + (size_t)p1.x * 4;
      float4 a0 = r0[0], a1 = r0[1], a2 = r0[2], a3 = r0[3];
      float4 b0 = r1[0], b1 = r1[1], b2 = r1[2], b3 = r1[3];
      float n0 = __int_as_float(p0.y), n1 = __int_as_float(p1.y);
      float f[8];
      unpack8(a0, f);
#pragma unroll
      for (int i = 0; i < 8; ++i) acc[i] += n0 * f[i];
      unpack8(a1, f);
#pragma unroll
      for (int i = 0; i < 8; ++i) acc[8 + i] += n0 * f[i];
      unpack8(a2, f);
#pragma unroll
      for (int i = 0; i < 8; ++i) acc[16 + i] += n0 * f[i];
      unpack8(a3, f);
#pragma unroll
      for (int i = 0; i < 8; ++i) acc[24 + i] += n0 * f[i];
      unpack8(b0, f);
#pragma unroll
      for (int i = 0; i < 8; ++i) acc[i] += n1 * f[i];
      unpack8(b1, f);
#pragma unroll
      for (int i = 0; i < 8; ++i) acc[8 + i] += n1 * f[i];
      unpack8(b2, f);
#pragma unroll
      for (int i = 0; i < 8; ++i) acc[16 + i] += n1 * f[i];
      unpack8(b3, f);
#pragma unroll
      for (int i = 0; i < 8; ++i) acc[24 + i] += n1 * f[i];
    }
    for (; e < end; ++e) {
      int2 p = pk[e];
      const float4* r0 = Tp + (size_t)p.x * 4;
      float nm = __int_as_float(p.y);
      float f[8];
#pragma unroll
      for (int rqi = 0; rqi < 4; ++rqi) {
        unpack8(r0[rqi], f);
#pragma unroll
        for (int i = 0; i < 8; ++i) acc[rqi * 8 + i] += nm * f[i];
      }
    }
    const float4* Xr = reinterpret_cast<const float4*>(X1p) + ((size_t)g * NN + n) * 4;
    float4 xr[4];
#pragma unroll
    for (int qd = 0; qd < 4; ++qd) xr[qd] = nt_load4(Xr + qd);
    const float4* Tr = Tp + (size_t)n * 4;
    float4* dst = reinterpret_cast<float4*>(P1) + ((size_t)(l * 16 + g) * NN + n) * 4;
#pragma unroll
    for (int qd = 0; qd < 4; ++qd) {
      float xv[8], tv[8];
      unpack8(xr[qd], xv);
      unpack8(Tr[qd], tv);
      float z[8];
#pragma unroll
      for (int d = 0; d < 8; ++d) z[d] = bs[d];
#pragma unroll
      for (int c = 0; c < 8; ++c) {
        float xc = xv[c], tc = tv[c], ac = acc[qd * 8 + c];
#pragma unroll
        for (int d = 0; d < 8; ++d)
          z[d] += xc * wx[c * 8 + d] + tc * w1[c * 8 + d] + ac * w2[c * 8 + d];
      }
      nt_store4(dst + qd, pack8(z));
    }
  }
}

// ---------------- block2 align(1x1)+GLU: P1 planes -> X2nh node-major [n][32][12] fp16 ----------------
__global__ __launch_bounds__(256) void glu2_kernel(const __half* __restrict__ P1,
                                                   const float* __restrict__ w2, const float* __restrict__ b2,
                                                   const float* __restrict__ aw, const float* __restrict__ ab,
                                                   __half* __restrict__ X2nh) {
  __shared__ float w2s[22 * 16 * 3], b2s[22], aws[11 * 16], abs_[11];
  for (int i = threadIdx.x; i < 22 * 16 * 3; i += 256) w2s[i] = w2[i];
  if (threadIdx.x < 22) b2s[threadIdx.x] = b2[threadIdx.x];
  for (int i = threadIdx.x; i < 11 * 16; i += 256) aws[i] = aw[i];
  if (threadIdx.x < 11) abs_[threadIdx.x] = ab[threadIdx.x];
  __syncthreads();
  int idx = blockIdx.x * 256 + threadIdx.x;   // idx = n*32 + s2, s2 = b*2 + t
  int n = idx >> 5, s2 = idx & 31;
  int b = s2 >> 1, t = s2 & 1;
  const float4* P4 = reinterpret_cast<const float4*>(P1);
  size_t base0 = ((size_t)(0 * 16 + b) * NN + n) * 4 + t;
  size_t base1 = ((size_t)(1 * 16 + b) * NN + n) * 4 + t;
  size_t base2 = ((size_t)(2 * 16 + b) * NN + n) * 4 + t;
  size_t base3 = ((size_t)(3 * 16 + b) * NN + n) * 4 + t;
  float hv[24], tv[24], tmp[8];
#pragma unroll
  for (int k = 0; k < 3; ++k) {
    unpack8(P4[base0 + k], hv + 8 * k);
    unpack8(P4[base1 + k], tmp);
#pragma unroll
    for (int i = 0; i < 8; ++i) hv[8 * k + i] += tmp[i];
    unpack8(P4[base2 + k], tv + 8 * k);
    unpack8(P4[base3 + k], tmp);
#pragma unroll
    for (int i = 0; i < 8; ++i) tv[8 * k + i] += tmp[i];
  }
  float o[12];
  o[11] = 0.f;
#pragma unroll
  for (int co = 0; co < 11; ++co) {
    float p = b2s[co], q = b2s[co + 11], a = abs_[co];
#pragma unroll
    for (int ci = 0; ci < 16; ++ci) {
      float v0 = (ci < 8) ? hv[ci] : tv[ci - 8];
      float v1 = (ci < 8) ? hv[8 + ci] : tv[ci];
      float v2 = (ci < 8) ? hv[16 + ci] : tv[8 + ci];
      p += w2s[(co * 16 + ci) * 3 + 0] * v0 + w2s[(co * 16 + ci) * 3 + 1] * v1 +
           w2s[(co * 16 + ci) * 3 + 2] * v2;
      q += w2s[((co + 11) * 16 + ci) * 3 + 0] * v0 + w2s[((co + 11) * 16 + ci) * 3 + 1] * v1 +
           w2s[((co + 11) * 16 + ci) * 3 + 2] * v2;
      a += aws[co * 16 + ci] * v2;
    }
    o[co] = (p + a) * sigmoidf_(q);
  }
  float2* o2 = reinterpret_cast<float2*>(X2nh) + (long)idx * 3;
  o2[0] = pack4(o);
  o2[1] = pack4(o + 4);
  o2[2] = pack4(o + 8);
}

// ---------------- block2 pull (round-6): all 4 lists, 768B node-major rows, unroll-4 ----------------
__global__ __launch_bounds__(256) void pull2_kernel(const int* __restrict__ csrBase,
                                                    const __half* __restrict__ Xh,
                                                    __half* __restrict__ T1hAll) {
  int gtid = blockIdx.x * 256 + threadIdx.x;
  int l = gtid / (NN * 96);
  int t = gtid - l * (NN * 96);
  int n = t / 96, j = t - n * 96;
  const int* rp = CSR_RP(csrBase, l);
  const int2* pk = CSR_PK(csrBase, l);
  const float2* in2 = reinterpret_cast<const float2*>(Xh);
  float acc[4];
#pragma unroll
  for (int i = 0; i < 4; ++i) acc[i] = 0.f;
  int e = rp[n], end = rp[n + 1];
  for (; e + 4 <= end; e += 4) {
    int2 p0 = pk[e], p1 = pk[e + 1], p2 = pk[e + 2], p3 = pk[e + 3];
    float2 v0 = in2[(long)p0.x * 96 + j];
    float2 v1 = in2[(long)p1.x * 96 + j];
    float2 v2 = in2[(long)p2.x * 96 + j];
    float2 v3 = in2[(long)p3.x * 96 + j];
    float f[4];
    float n0 = __int_as_float(p0.y), n1 = __int_as_float(p1.y);
    float n2 = __int_as_float(p2.y), n3 = __int_as_float(p3.y);
    unpack4(v0, f);
#pragma unroll
    for (int i = 0; i < 4; ++i) acc[i] -= n0 * f[i];
    unpack4(v1, f);
#pragma unroll
    for (int i = 0; i < 4; ++i) acc[i] -= n1 * f[i];
    unpack4(v2, f);
#pragma unroll
    for (int i = 0; i < 4; ++i) acc[i] -= n2 * f[i];
    unpack4(v3, f);
#pragma unroll
    for (int i = 0; i < 4; ++i) acc[i] -= n3 * f[i];
  }
  for (; e < end; ++e) {
    int2 p = pk[e];
    float2 v = in2[(long)p.x * 96 + j];
    float nm = __int_as_float(p.y);
    float f[4];
    unpack4(v, f);
#pragma unroll
    for (int i = 0; i < 4; ++i) acc[i] -= nm * f[i];
  }
  reinterpret_cast<float2*>(T1hAll)[(size_t)l * (T1SLOT / 4) + t] = pack4(acc);
}

// ---------------- block2 fused Cheb combine (round-6): BOTH etypes, single write ----------------
__global__ __launch_bounds__(256) void cheb2_kernel(const int* __restrict__ csrBase,
    const __half* __restrict__ Xh, const __half* __restrict__ T1hAll,
    const float* __restrict__ Whg, const float* __restrict__ bhg,
    const float* __restrict__ Wtg, const float* __restrict__ btg,
    __half* __restrict__ outH, __half* __restrict__ outT) {
  constexpr int C = 11, CC = 121;
  __shared__ float wx[CC], w1a[CC], w1b[CC], w2a[CC], w2b[CC], bs[C];
  int gtid = blockIdx.x * 256 + threadIdx.x;
  int g = gtid / (NN * 32);
  int tid = gtid - g * (NN * 32);
  const float* W = g ? Wtg : Whg;
  const float* bias = g ? btg : bhg;
  for (int i = threadIdx.x; i < CC; i += 256) {
    float w0A = W[i], w1A = W[CC + i], w2A = W[2 * CC + i];
    float w0B = W[3 * CC + i], w1B = W[4 * CC + i], w2B = W[5 * CC + i];
    wx[i] = w0A - w2A + w0B - w2B;
    w1a[i] = w1A; w1b[i] = w1B;
    w2a[i] = -2.f * w2A; w2b[i] = -2.f * w2B;
  }
  if (threadIdx.x < C) bs[threadIdx.x] = bias[threadIdx.x] + bias[C + threadIdx.x];
  __syncthreads();
  int n = tid >> 5, s = tid & 31;
  int s3 = s * 3;
  int l0 = 2 * g, l1 = 2 * g + 1;
  const int* rp0 = CSR_RP(csrBase, l0); const int2* pk0 = CSR_PK(csrBase, l0);
  const int* rp1 = CSR_RP(csrBase, l1); const int2* pk1 = CSR_PK(csrBase, l1);
  const float2* A2v = reinterpret_cast<const float2*>(T1hAll + (size_t)l0 * T1SLOT);
  const float2* B2v = reinterpret_cast<const float2*>(T1hAll + (size_t)l1 * T1SLOT);
  float acc0[12], acc1[12];
#pragma unroll
  for (int c = 0; c < 12; ++c) { acc0[c] = 0.f; acc1[c] = 0.f; }
  {
    int e = rp0[n], end = rp0[n + 1];
    for (; e + 2 <= end; e += 2) {
      int2 p0 = pk0[e], p1 = pk0[e + 1];
      long r0 = (long)p0.x * 96 + s3, r1 = (long)p1.x * 96 + s3;
      float2 a0 = A2v[r0], a1 = A2v[r0 + 1], a2 = A2v[r0 + 2];
      float2 b0 = A2v[r1], b1 = A2v[r1 + 1], b2 = A2v[r1 + 2];
      float n0 = __int_as_float(p0.y), n1 = __int_as_float(p1.y);
      float f[4];
      unpack4(a0, f);
#pragma unroll
      for (int i = 0; i < 4; ++i) acc0[i] += n0 * f[i];
      unpack4(a1, f);
#pragma unroll
      for (int i = 0; i < 4; ++i) acc0[4 + i] += n0 * f[i];
      unpack4(a2, f);
#pragma unroll
      for (int i = 0; i < 4; ++i) acc0[8 + i] += n0 * f[i];
      unpack4(b0, f);
#pragma unroll
      for (int i = 0; i < 4; ++i) acc0[i] += n1 * f[i];
      unpack4(b1, f);
#pragma unroll
      for (int i = 0; i < 4; ++i) acc0[4 + i] += n1 * f[i];
      unpack4(b2, f);
#pragma unroll
      for (int i = 0; i < 4; ++i) acc0[8 + i] += n1 * f[i];
    }
    for (; e < end; ++e) {
      int2 p = pk0[e];
      long r = (long)p.x * 96 + s3;
      float2 a0 = A2v[r], a1 = A2v[r + 1], a2 = A2v[r + 2];
      float nm = __int_as_float(p.y);
      float f[4];
      unpack4(a0, f);
#pragma unroll
      for (int i = 0; i < 4; ++i) acc0[i] += nm * f[i];
      unpack4(a1, f);
#pragma unroll
      for (int i = 0; i < 4; ++i) acc0[4 + i] += nm * f[i];
      unpack4(a2, f);
#pragma unroll
      for (int i = 0; i < 4; ++i) acc0[8 + i] += nm * f[i];
    }
  }
  {
    int e = rp1[n], end = rp1[n + 1];
    for (; e + 2 <= end; e += 2) {
      int2 p0 = pk1[e], p1 = pk1[e + 1];
      long r0 = (long)p0.x * 96 + s3, r1 = (long)p1.x * 96 + s3;
      float2 a0 = B2v[r0], a1 = B2v[r0 + 1], a2 = B2v[r0 + 2];
      float2 b0 = B2v[r1], b1 = B2v[r1 + 1], b2 = B2v[r1 + 2];
      float n0 = __int_as_float(p0.y), n1 = __int_as_float(p1.y);
      float f[4];
      unpack4(a0, f);
#pragma unroll
      for (int i = 0; i < 4; ++i) acc1[i] += n0 * f[i];
      unpack4(a1, f);
#pragma unroll
      for (int i = 0; i < 4; ++i) acc1[4 + i] += n0 * f[i];
      unpack4(a2, f);
#pragma unroll
      for (int i = 0; i < 4; ++i) acc1[8 + i] += n0 * f[i];
      unpack4(b0, f);
#pragma unroll
      for (int i = 0; i < 4; ++i) acc1[i] += n1 * f[i];
      unpack4(b1, f);
#pragma unroll
      for (int i = 0; i < 4; ++i) acc1[4 + i] += n1 * f[i];
      unpack4(b2, f);
#pragma unroll
      for (int i = 0; i < 4; ++i) acc1[8 + i] += n1 * f[i];
    }
    for (; e < end; ++e) {
      int2 p = pk1[e];
      long r = (long)p.x * 96 + s3;
      float2 a0 = B2v[r], a1 = B2v[r + 1], a2 = B2v[r + 2];
      float nm = __int_as_float(p.y);
      float f[4];
      unpack4(a0, f);
#pragma unroll
      for (int i = 0; i < 4; ++i) acc1[i] += nm * f[i];
      unpack4(a1, f);
#pragma unroll
      for (int i = 0; i < 4; ++i) acc1[4 + i] += nm * f[i];
      unpack4(a2, f);
#pragma unroll
      for (int i = 0; i < 4; ++i) acc1[8 + i] += nm * f[i];
    }
  }
  float z[12];
#pragma unroll
  for (int d = 0; d < C; ++d) z[d] = bs[d];
  z[11] = 0.f;
  const float2* X2v = reinterpret_cast<const float2*>(Xh);
  long own = (long)tid * 3;
#pragma unroll
  for (int q = 0; q < 3; ++q) {
    float xv[4], av[4], bv[4];
    unpack4(X2v[own + q], xv);
    unpack4(A2v[own + q], av);
    unpack4(B2v[own + q], bv);
#pragma unroll
    for (int k = 0; k < 4; ++k) {
      int c = q * 4 + k;
      if (c == 11) continue;
      float x0c = xv[k], tac = av[k], tbc = bv[k], a0 = acc0[c], a1 = acc1[c];
#pragma unroll
      for (int d = 0; d < C; ++d)
        z[d] += x0c * wx[c * C + d] + tac * w1a[c * C + d] + tbc * w1b[c * C + d] +
                a0 * w2a[c * C + d] + a1 * w2b[c * C + d];
    }
  }
  float2* o2 = reinterpret_cast<float2*>(g ? outT : outH) + (long)tid * 3;
  o2[0] = pack4(z);
  o2[1] = pack4(z + 4);
  o2[2] = pack4(z + 8);
}

// ---------------- final: grid-stride; out[r,:] = z[r,:44] @ W[44,128] + bias ----------------
__global__ __launch_bounds__(256) void final_kernel(const __half* __restrict__ H2, const __half* __restrict__ T2b,
                                                    const float* __restrict__ W, const float* __restrict__ bias,
                                                    float* __restrict__ out) {
  __shared__ __half zsr[64][48];
  int tid = threadIdx.x;
  int c = tid & 127, h = tid >> 7;
  float wp[48];
#pragma unroll
  for (int off = 0; off < 48; ++off) {
    int half_ = off / 24, r_ = off - half_ * 24;
    int t = r_ / 12, c_ = r_ - t * 12;
    wp[off] = (c_ == 11) ? 0.f : W[(2 * (c_ + half_ * 11) + t) * 128 + c];
  }
  float bh = bias[c];
  for (int tile = blockIdx.x; tile < 7500; tile += gridDim.x) {
    long r0 = (long)tile * 64;
    __syncthreads();
#pragma unroll
    for (int it = 0; it < 2; ++it) {
      int item = it * 256 + tid;          // 384 items = 64 rows x 6 float4
      if (item < 384) {
        int row = item / 6, piece = item - row * 6;
        long r = r0 + row;
        int b = (int)(r / NN), n = (int)(r - (long)b * NN);
        const float4* srcb = reinterpret_cast<const float4*>(piece < 3 ? H2 : T2b);
        int f4i = (piece < 3) ? piece : piece - 3;
        float4 v = srcb[(long)n * 48 + b * 3 + f4i];
        *reinterpret_cast<float4*>(&zsr[row][(piece < 3 ? 0 : 24) + f4i * 8]) = v;
      }
    }
    __syncthreads();
    int rbeg = h * 32;
#pragma unroll 2
    for (int row = rbeg; row < rbeg + 32; ++row) {
      const float4* zr4 = reinterpret_cast<const float4*>(&zsr[row][0]);
      float acc = bh;
#pragma unroll
      for (int q = 0; q < 6; ++q) {
        F4H8 u; u.v = zr4[q];
#pragma unroll
        for (int i = 0; i < 8; ++i)
          acc = fmaf(__half2float(u.h[i]), wp[q * 8 + i], acc);
      }
      out[(r0 + row) * 128 + c] = acc;
    }
  }
}

extern "C" void kernel_launch(void* const* d_in, const int* in_sizes, int n_in,
                              void* d_out, int out_size, void* d_ws, size_t ws_size,
                              hipStream_t stream) {
  const float* x    = (const float*)d_in[0];
  const int*   hg   = (const int*)d_in[1];
  const int*   tg   = (const int*)d_in[2];
  const float* t1w  = (const float*)d_in[3];
  const float* t1b  = (const float*)d_in[4];
  const float* h1W  = (const float*)d_in[5];
  const float* h1b  = (const float*)d_in[6];
  const float* g1W  = (const float*)d_in[7];
  const float* g1b  = (const float*)d_in[8];
  const float* a2w  = (const float*)d_in[9];
  const float* a2b  = (const float*)d_in[10];
  const float* t2w  = (const float*)d_in[11];
  const float* t2b  = (const float*)d_in[12];
  const float* h2W  = (const float*)d_in[13];
  const float* h2b  = (const float*)d_in[14];
  const float* g2W  = (const float*)d_in[15];
  const float* g2b  = (const float*)d_in[16];
  const float* outw = (const float*)d_in[17];
  const float* outb = (const float*)d_in[18];
  float* out = (float*)d_out;

  // workspace layout (aliased regions)
  __half* T1p  = (__half*)d_ws;               // 4*T1SLOT: block1 T1 planes; later Cfh/Dfh
  __half* Cfh  = T1p;                          // block2 out (hg) node-major [n][32][12]
  __half* Dfh  = T1p + 11520000;               // block2 out (tg)
  __half* X1p  = T1p + 4L * T1SLOT;            // 1*T1SLOT: X1 planes; later X2nh node-major
  __half* X2nh = X1p;
  __half* P1   = X1p + T1SLOT;                 // 4*T1SLOT: block1 partial planes; later T1h2
  __half* T1h2 = P1;
  int* csrBase  = (int*)(P1 + 4L * T1SLOT);    // 4 * CSR_STRIDE ints
  // CSR-build scratch aliased into P1 (dead before cheb1 writes P1)
  int* degO     = (int*)P1;                    // 4*NN
  int* degI     = degO + 4 * NN;               // 4*NN
  int* cursor   = degI + 4 * NN;               // 4*NN
  int* partials = cursor + 4 * NN;             // 4*NCH

  // --- build CSR (sorted by dst) + norms for all 4 edge lists, batched ---
  hipMemsetAsync(degO, 0, 8 * NN * sizeof(int), stream);
  count_all_kernel<<<(4 * EDGES + 255) / 256, 256, 0, stream>>>(hg, tg, degO, degI);
  scan1_kernel<<<4 * NCH, 256, 0, stream>>>(degI, csrBase, partials);
  scan2_kernel<<<1, 128, 0, stream>>>(partials);
  fixup_kernel<<<4 * NCH, 256, 0, stream>>>(csrBase, cursor, partials);
  fill_all_kernel<<<(4 * EDGES + 255) / 256, 256, 0, stream>>>(hg, tg, degO, degI, cursor, csrBase);

  // --- block1 (plane-major, XCD-pinned) ---
  glu1_kernel<<<16 * NN * 4 / 256, 256, 0, stream>>>(x, t1w, t1b, X1p);
  pull1_kernel<<<2048, 256, 0, stream>>>(csrBase, X1p, T1p);
  cheb1_kernel<<<2048, 256, 0, stream>>>(csrBase, X1p, T1p, h1W, h1b, g1W, g1b, P1);

  // --- block2 (node-major, round-6 structure) ---
  glu2_kernel<<<NN * 32 / 256, 256, 0, stream>>>(P1, t2w, t2b, a2w, a2b, X2nh);
  pull2_kernel<<<4 * NN * 96 / 256, 256, 0, stream>>>(csrBase, X2nh, T1h2);
  cheb2_kernel<<<2 * NN * 32 / 256, 256, 0, stream>>>(csrBase, X2nh, T1h2, h2W, h2b, g2W, g2b, Cfh, Dfh);

  // --- final linear ---
  final_kernel<<<1024, 256, 0, stream>>>(Cfh, Dfh, outw, outb, out);
}

// Round 10
// 958.075 us; speedup vs baseline: 1.3890x; 1.3890x over previous
//
#include <hip/hip_runtime.h>
#include <hip/hip_fp16.h>
#include <math.h>

#define EDGES 120000
#define NN    30000
#define NCH   118   // ceil(30000/256)
#define T1SLOT 15360000   // halfs per slot (NN*64*8)

__device__ __forceinline__ float sigmoidf_(float x) { return 1.f / (1.f + __expf(-x)); }

union F4H8 { float4 v; __half h[8]; };
union F2H4 { float2 v; __half h[4]; };

__device__ __forceinline__ void unpack8(float4 v, float* f) {
  F4H8 u; u.v = v;
#pragma unroll
  for (int i = 0; i < 8; ++i) f[i] = __half2float(u.h[i]);
}
__device__ __forceinline__ float4 pack8(const float* f) {
  F4H8 u;
#pragma unroll
  for (int i = 0; i < 8; ++i) u.h[i] = __float2half(f[i]);
  return u.v;
}
__device__ __forceinline__ void unpack4(float2 v, float* f) {
  F2H4 u; u.v = v;
#pragma unroll
  for (int i = 0; i < 4; ++i) f[i] = __half2float(u.h[i]);
}
__device__ __forceinline__ float2 pack4(const float* f) {
  F2H4 u;
#pragma unroll
  for (int i = 0; i < 4; ++i) u.h[i] = __float2half(f[i]);
  return u.v;
}

// CSR slot layout (ints): rowptr[30016] | pack int2[120000] (src, norm-bits)
#define CSR_STRIDE 270016
#define CSR_RP(base, l)   ((base) + (size_t)(l) * CSR_STRIDE)
#define CSR_PK(base, l)   ((const int2*)((base) + (size_t)(l) * CSR_STRIDE + 30016))
#define CSR_PKW(base, l)  ((int2*)((base) + (size_t)(l) * CSR_STRIDE + 30016))

// ---------------- CSR build ----------------
__global__ void count_all_kernel(const int* __restrict__ hg, const int* __restrict__ tg,
                                 int* __restrict__ degO, int* __restrict__ degI) {
  int tid = blockIdx.x * blockDim.x + threadIdx.x;
  if (tid >= 4 * EDGES) return;
  int l = tid / EDGES, j = tid - l * EDGES;
  const int* G = (l < 2) ? hg : tg;
  const int* src = G + (size_t)(l & 1) * 2 * EDGES;
  const int* dst = src + EDGES;
  atomicAdd(&degO[l * NN + src[j]], 1);
  atomicAdd(&degI[l * NN + dst[j]], 1);
}

__global__ __launch_bounds__(256) void scan1_kernel(const int* __restrict__ degI,
                                                    int* __restrict__ csrBase,
                                                    int* __restrict__ partials) {
  int l = blockIdx.x / NCH, ch = blockIdx.x - l * NCH;
  int tid = threadIdx.x;
  int i = ch * 256 + tid;
  __shared__ int buf[256];
  int v = (i < NN) ? degI[l * NN + i] : 0;
  buf[tid] = v;
  __syncthreads();
  for (int off = 1; off < 256; off <<= 1) {
    int t = (tid >= off) ? buf[tid - off] : 0;
    __syncthreads();
    buf[tid] += t;
    __syncthreads();
  }
  int* rp = CSR_RP(csrBase, l);
  if (i < NN) rp[i + 1] = buf[tid];
  if (tid == 255) partials[l * NCH + ch] = buf[255];
}

__global__ __launch_bounds__(128) void scan2_kernel(int* __restrict__ partials) {
  __shared__ int buf[128];
  int tid = threadIdx.x;
  for (int l = 0; l < 4; ++l) {
    int v = (tid < NCH) ? partials[l * NCH + tid] : 0;
    buf[tid] = v;
    __syncthreads();
    for (int off = 1; off < 128; off <<= 1) {
      int t = (tid >= off) ? buf[tid - off] : 0;
      __syncthreads();
      buf[tid] += t;
      __syncthreads();
    }
    if (tid < NCH) partials[l * NCH + tid] = buf[tid] - v;  // exclusive
    __syncthreads();
  }
}

__global__ __launch_bounds__(256) void fixup_kernel(int* __restrict__ csrBase,
                                                    int* __restrict__ cursor,
                                                    const int* __restrict__ partials) {
  int l = blockIdx.x / NCH, ch = blockIdx.x - l * NCH;
  int i = ch * 256 + threadIdx.x;
  int* rp = CSR_RP(csrBase, l);
  int off = partials[l * NCH + ch];
  if (i < NN) {
    int val = rp[i + 1] + off;
    rp[i + 1] = val;
    if (i + 1 < NN) cursor[l * NN + i + 1] = val;
  }
  if (i == 0) { rp[0] = 0; cursor[l * NN] = 0; }
}

__global__ void fill_all_kernel(const int* __restrict__ hg, const int* __restrict__ tg,
                                const int* __restrict__ degO, const int* __restrict__ degI,
                                int* __restrict__ cursor, int* __restrict__ csrBase) {
  int tid = blockIdx.x * blockDim.x + threadIdx.x;
  if (tid >= 4 * EDGES) return;
  int l = tid / EDGES, j = tid - l * EDGES;
  const int* G = (l < 2) ? hg : tg;
  const int* src = G + (size_t)(l & 1) * 2 * EDGES;
  const int* dst = src + EDGES;
  int s = src[j], d = dst[j];
  int doo = degO[l * NN + s]; if (doo < 1) doo = 1;
  int dii = degI[l * NN + d]; if (dii < 1) dii = 1;
  float nm = rsqrtf((float)doo) * rsqrtf((float)dii);
  int p = atomicAdd(&cursor[l * NN + d], 1);
  CSR_PKW(csrBase, l)[p] = make_int2(s, __float_as_int(nm));
}

// ---------------- block1 temporal GLU conv: x[B,N,6,1] -> X1h [N][64][8] fp16 ----------------
__global__ void glu1_kernel(const float* __restrict__ x, const float* __restrict__ w,
                            const float* __restrict__ b, __half* __restrict__ X1h) {
  int idx = blockIdx.x * blockDim.x + threadIdx.x;   // idx = n*64 + s, s = b*4 + t
  if (idx >= NN * 64) return;
  int n = idx >> 6, s = idx & 63;
  int bb = s >> 2, t = s & 3;
  const float* xb = x + ((long)bb * NN + n) * 6;
  float x0 = xb[t], x1 = xb[t + 1], x2 = xb[t + 2];
  float o[8];
#pragma unroll
  for (int c = 0; c < 8; ++c) {
    float p = w[c * 3 + 0] * x0 + w[c * 3 + 1] * x1 + w[c * 3 + 2] * x2 + b[c];
    float q = w[(c + 8) * 3 + 0] * x0 + w[(c + 8) * 3 + 1] * x1 + w[(c + 8) * 3 + 2] * x2 + b[c + 8];
    float al = (c == 0) ? x2 : 0.f;
    o[c] = (p + al) * sigmoidf_(q);
  }
  reinterpret_cast<float4*>(X1h)[idx] = pack8(o);
}

// ---------------- block1 pull (batched: all 4 lists gather the SHARED X1 buffer) ----------------
__global__ __launch_bounds__(256) void pull1_kernel(const int* __restrict__ csrBase,
                                                    const __half* __restrict__ Xh,
                                                    __half* __restrict__ T1hAll) {
  int gtid = blockIdx.x * 256 + threadIdx.x;
  int l = gtid / (NN * 64);
  int t = gtid - l * (NN * 64);
  int n = t >> 6, j = t & 63;
  const int* rp = CSR_RP(csrBase, l);
  const int2* pk = CSR_PK(csrBase, l);
  const float4* in4 = reinterpret_cast<const float4*>(Xh);
  float acc[8];
#pragma unroll
  for (int i = 0; i < 8; ++i) acc[i] = 0.f;
  int e = rp[n], end = rp[n + 1];
  for (; e + 4 <= end; e += 4) {
    int2 p0 = pk[e], p1 = pk[e + 1], p2 = pk[e + 2], p3 = pk[e + 3];
    float4 v0 = in4[(long)p0.x * 64 + j];
    float4 v1 = in4[(long)p1.x * 64 + j];
    float4 v2 = in4[(long)p2.x * 64 + j];
    float4 v3 = in4[(long)p3.x * 64 + j];
    float f[8];
    float n0 = __int_as_float(p0.y), n1 = __int_as_float(p1.y);
    float n2 = __int_as_float(p2.y), n3 = __int_as_float(p3.y);
    unpack8(v0, f);
#pragma unroll
    for (int i = 0; i < 8; ++i) acc[i] -= n0 * f[i];
    unpack8(v1, f);
#pragma unroll
    for (int i = 0; i < 8; ++i) acc[i] -= n1 * f[i];
    unpack8(v2, f);
#pragma unroll
    for (int i = 0; i < 8; ++i) acc[i] -= n2 * f[i];
    unpack8(v3, f);
#pragma unroll
    for (int i = 0; i < 8; ++i) acc[i] -= n3 * f[i];
  }
  for (; e < end; ++e) {
    int2 p = pk[e];
    float4 v = in4[(long)p.x * 64 + j];
    float nm = __int_as_float(p.y);
    float f[8];
    unpack8(v, f);
#pragma unroll
    for (int i = 0; i < 8; ++i) acc[i] -= nm * f[i];
  }
  reinterpret_cast<float4*>(T1hAll)[(size_t)l * (T1SLOT / 8) + t] = pack8(acc);
}

// ---------------- block1 Cheb partial: ONE list per LAUNCH (single 30MB gather buffer) ----------
// P[l] = X*(W0-W2) + T1own*W1 + gather_l(T1[l])*(-2W2) + bias
__global__ __launch_bounds__(256) void cheb1_kernel(const int* __restrict__ rp, const int2* __restrict__ pk,
    const __half* __restrict__ Xh, const __half* __restrict__ T1l,
    const float* __restrict__ W, const float* __restrict__ bias,
    __half* __restrict__ Pl) {
  constexpr int C = 8, CC = 64;
  __shared__ float wx[CC], w1[CC], w2[CC], bs[C];
  for (int i = threadIdx.x; i < CC; i += 256) {
    float w0v = W[i], w1v = W[CC + i], w2v = W[2 * CC + i];
    wx[i] = w0v - w2v; w1[i] = w1v; w2[i] = -2.f * w2v;
  }
  if (threadIdx.x < C) bs[threadIdx.x] = bias[threadIdx.x];
  __syncthreads();
  int tid = blockIdx.x * 256 + threadIdx.x;
  int n = tid >> 6, s = tid & 63;
  const float4* T4 = reinterpret_cast<const float4*>(T1l);
  float acc[C];
#pragma unroll
  for (int c = 0; c < C; ++c) acc[c] = 0.f;
  int e = rp[n], end = rp[n + 1];
  for (; e + 4 <= end; e += 4) {
    int2 p0 = pk[e], p1 = pk[e + 1], p2 = pk[e + 2], p3 = pk[e + 3];
    float4 v0 = T4[(long)p0.x * 64 + s];
    float4 v1 = T4[(long)p1.x * 64 + s];
    float4 v2 = T4[(long)p2.x * 64 + s];
    float4 v3 = T4[(long)p3.x * 64 + s];
    float n0 = __int_as_float(p0.y), n1 = __int_as_float(p1.y);
    float n2 = __int_as_float(p2.y), n3 = __int_as_float(p3.y);
    float f[8];
    unpack8(v0, f);
#pragma unroll
    for (int c = 0; c < C; ++c) acc[c] += n0 * f[c];
    unpack8(v1, f);
#pragma unroll
    for (int c = 0; c < C; ++c) acc[c] += n1 * f[c];
    unpack8(v2, f);
#pragma unroll
    for (int c = 0; c < C; ++c) acc[c] += n2 * f[c];
    unpack8(v3, f);
#pragma unroll
    for (int c = 0; c < C; ++c) acc[c] += n3 * f[c];
  }
  for (; e < end; ++e) {
    int2 p = pk[e];
    float4 v = T4[(long)p.x * 64 + s];
    float nm = __int_as_float(p.y);
    float f[8];
    unpack8(v, f);
#pragma unroll
    for (int c = 0; c < C; ++c) acc[c] += nm * f[c];
  }
  float xv[C], tv[C];
  unpack8(reinterpret_cast<const float4*>(Xh)[tid], xv);
  unpack8(T4[tid], tv);
  float z[C];
#pragma unroll
  for (int d = 0; d < C; ++d) z[d] = bs[d];
#pragma unroll
  for (int c = 0; c < C; ++c) {
    float xc = xv[c], tc = tv[c], ac = acc[c];
#pragma unroll
    for (int d = 0; d < C; ++d)
      z[d] += xc * wx[c * C + d] + tc * w1[c * C + d] + ac * w2[c * C + d];
  }
  reinterpret_cast<float4*>(Pl)[tid] = pack8(z);
}

// ---------------- block2 align(1x1)+GLU: 4 partials [N][64][8] -> X2nh [N][32][12] fp16 ----------------
__global__ __launch_bounds__(256) void glu2_kernel(const __half* __restrict__ P,
                                                   const float* __restrict__ w2, const float* __restrict__ b2,
                                                   const float* __restrict__ aw, const float* __restrict__ ab,
                                                   __half* __restrict__ X2nh) {
  __shared__ float w2s[22 * 16 * 3], b2s[22], aws[11 * 16], abs_[11];
  for (int i = threadIdx.x; i < 22 * 16 * 3; i += 256) w2s[i] = w2[i];
  if (threadIdx.x < 22) b2s[threadIdx.x] = b2[threadIdx.x];
  for (int i = threadIdx.x; i < 11 * 16; i += 256) aws[i] = aw[i];
  if (threadIdx.x < 11) abs_[threadIdx.x] = ab[threadIdx.x];
  __syncthreads();
  int idx = blockIdx.x * 256 + threadIdx.x;   // idx = n*32 + s2, s2 = b*2 + t
  int n = idx >> 5, s = idx & 31;
  int bb = s >> 1, t = s & 1;
  long rbase = (long)n * 64 + bb * 4 + t;     // float4 row index (8 halfs per slice)
  const float4* H0 = reinterpret_cast<const float4*>(P) + rbase;
  const float4* H1 = reinterpret_cast<const float4*>(P + (size_t)T1SLOT) + rbase;
  const float4* Ta = reinterpret_cast<const float4*>(P + 2 * (size_t)T1SLOT) + rbase;
  const float4* Tb = reinterpret_cast<const float4*>(P + 3 * (size_t)T1SLOT) + rbase;
  float hv[24], tv[24], tmp[8];
#pragma unroll
  for (int q = 0; q < 3; ++q) {
    unpack8(H0[q], hv + 8 * q); unpack8(H1[q], tmp);
#pragma unroll
    for (int i = 0; i < 8; ++i) hv[8 * q + i] += tmp[i];
    unpack8(Ta[q], tv + 8 * q); unpack8(Tb[q], tmp);
#pragma unroll
    for (int i = 0; i < 8; ++i) tv[8 * q + i] += tmp[i];
  }
  float o[12];
  o[11] = 0.f;
#pragma unroll
  for (int co = 0; co < 11; ++co) {
    float p = b2s[co], q = b2s[co + 11], a = abs_[co];
#pragma unroll
    for (int ci = 0; ci < 16; ++ci) {
      float v0 = (ci < 8) ? hv[ci] : tv[ci - 8];
      float v1 = (ci < 8) ? hv[8 + ci] : tv[ci];
      float v2 = (ci < 8) ? hv[16 + ci] : tv[8 + ci];
      p += w2s[(co * 16 + ci) * 3 + 0] * v0 + w2s[(co * 16 + ci) * 3 + 1] * v1 +
           w2s[(co * 16 + ci) * 3 + 2] * v2;
      q += w2s[((co + 11) * 16 + ci) * 3 + 0] * v0 + w2s[((co + 11) * 16 + ci) * 3 + 1] * v1 +
           w2s[((co + 11) * 16 + ci) * 3 + 2] * v2;
      a += aws[co * 16 + ci] * v2;
    }
    o[co] = (p + a) * sigmoidf_(q);
  }
  float2* o2 = reinterpret_cast<float2*>(X2nh) + (long)idx * 3;
  o2[0] = pack4(o);
  o2[1] = pack4(o + 4);
  o2[2] = pack4(o + 8);
}

// ---------------- block2 pull (batched: all 4 lists gather the SHARED X2nh buffer) ----------------
__global__ __launch_bounds__(256) void pull2_kernel(const int* __restrict__ csrBase,
                                                    const __half* __restrict__ Xh,
                                                    __half* __restrict__ T1hAll) {
  int gtid = blockIdx.x * 256 + threadIdx.x;
  int l = gtid / (NN * 96);
  int t = gtid - l * (NN * 96);
  int n = t / 96, j = t - n * 96;
  const int* rp = CSR_RP(csrBase, l);
  const int2* pk = CSR_PK(csrBase, l);
  const float2* in2 = reinterpret_cast<const float2*>(Xh);
  float acc[4];
#pragma unroll
  for (int i = 0; i < 4; ++i) acc[i] = 0.f;
  int e = rp[n], end = rp[n + 1];
  for (; e + 4 <= end; e += 4) {
    int2 p0 = pk[e], p1 = pk[e + 1], p2 = pk[e + 2], p3 = pk[e + 3];
    float2 v0 = in2[(long)p0.x * 96 + j];
    float2 v1 = in2[(long)p1.x * 96 + j];
    float2 v2 = in2[(long)p2.x * 96 + j];
    float2 v3 = in2[(long)p3.x * 96 + j];
    float f[4];
    float n0 = __int_as_float(p0.y), n1 = __int_as_float(p1.y);
    float n2 = __int_as_float(p2.y), n3 = __int_as_float(p3.y);
    unpack4(v0, f);
#pragma unroll
    for (int i = 0; i < 4; ++i) acc[i] -= n0 * f[i];
    unpack4(v1, f);
#pragma unroll
    for (int i = 0; i < 4; ++i) acc[i] -= n1 * f[i];
    unpack4(v2, f);
#pragma unroll
    for (int i = 0; i < 4; ++i) acc[i] -= n2 * f[i];
    unpack4(v3, f);
#pragma unroll
    for (int i = 0; i < 4; ++i) acc[i] -= n3 * f[i];
  }
  for (; e < end; ++e) {
    int2 p = pk[e];
    float2 v = in2[(long)p.x * 96 + j];
    float nm = __int_as_float(p.y);
    float f[4];
    unpack4(v, f);
#pragma unroll
    for (int i = 0; i < 4; ++i) acc[i] -= nm * f[i];
  }
  reinterpret_cast<float2*>(T1hAll)[(size_t)l * (T1SLOT / 4) + t] = pack4(acc);
}

// ---------------- block2 Cheb partial: ONE list per LAUNCH (single 23MB gather buffer) ----------
__global__ __launch_bounds__(256) void cheb2_kernel(const int* __restrict__ rp, const int2* __restrict__ pk,
    const __half* __restrict__ Xh, const __half* __restrict__ T1l,
    const float* __restrict__ W, const float* __restrict__ bias,
    __half* __restrict__ P2l) {
  constexpr int C = 11, CC = 121;
  __shared__ float wx[CC], w1[CC], w2[CC], bs[C];
  for (int i = threadIdx.x; i < CC; i += 256) {
    float w0v = W[i], w1v = W[CC + i], w2v = W[2 * CC + i];
    wx[i] = w0v - w2v; w1[i] = w1v; w2[i] = -2.f * w2v;
  }
  if (threadIdx.x < C) bs[threadIdx.x] = bias[threadIdx.x];
  __syncthreads();
  int tid = blockIdx.x * 256 + threadIdx.x;
  int n = tid >> 5, s = tid & 31;
  int s3 = s * 3;
  const float2* A2v = reinterpret_cast<const float2*>(T1l);
  float acc[12];
#pragma unroll
  for (int c = 0; c < 12; ++c) acc[c] = 0.f;
  int e = rp[n], end = rp[n + 1];
  for (; e + 4 <= end; e += 4) {
    int2 p0 = pk[e], p1 = pk[e + 1], p2 = pk[e + 2], p3 = pk[e + 3];
    long r0 = (long)p0.x * 96 + s3, r1 = (long)p1.x * 96 + s3;
    long r2 = (long)p2.x * 96 + s3, r3 = (long)p3.x * 96 + s3;
    float2 a0 = A2v[r0], a1 = A2v[r0 + 1], a2 = A2v[r0 + 2];
    float2 b0 = A2v[r1], b1 = A2v[r1 + 1], b2 = A2v[r1 + 2];
    float2 c0 = A2v[r2], c1 = A2v[r2 + 1], c2 = A2v[r2 + 2];
    float2 d0 = A2v[r3], d1 = A2v[r3 + 1], d2 = A2v[r3 + 2];
    float n0 = __int_as_float(p0.y), n1 = __int_as_float(p1.y);
    float n2 = __int_as_float(p2.y), n3 = __int_as_float(p3.y);
    float f[4];
    unpack4(a0, f);
#pragma unroll
    for (int i = 0; i < 4; ++i) acc[i] += n0 * f[i];
    unpack4(a1, f);
#pragma unroll
    for (int i = 0; i < 4; ++i) acc[4 + i] += n0 * f[i];
    unpack4(a2, f);
#pragma unroll
    for (int i = 0; i < 4; ++i) acc[8 + i] += n0 * f[i];
    unpack4(b0, f);
#pragma unroll
    for (int i = 0; i < 4; ++i) acc[i] += n1 * f[i];
    unpack4(b1, f);
#pragma unroll
    for (int i = 0; i < 4; ++i) acc[4 + i] += n1 * f[i];
    unpack4(b2, f);
#pragma unroll
    for (int i = 0; i < 4; ++i) acc[8 + i] += n1 * f[i];
    unpack4(c0, f);
#pragma unroll
    for (int i = 0; i < 4; ++i) acc[i] += n2 * f[i];
    unpack4(c1, f);
#pragma unroll
    for (int i = 0; i < 4; ++i) acc[4 + i] += n2 * f[i];
    unpack4(c2, f);
#pragma unroll
    for (int i = 0; i < 4; ++i) acc[8 + i] += n2 * f[i];
    unpack4(d0, f);
#pragma unroll
    for (int i = 0; i < 4; ++i) acc[i] += n3 * f[i];
    unpack4(d1, f);
#pragma unroll
    for (int i = 0; i < 4; ++i) acc[4 + i] += n3 * f[i];
    unpack4(d2, f);
#pragma unroll
    for (int i = 0; i < 4; ++i) acc[8 + i] += n3 * f[i];
  }
  for (; e < end; ++e) {
    int2 p = pk[e];
    long r = (long)p.x * 96 + s3;
    float2 a0 = A2v[r], a1 = A2v[r + 1], a2 = A2v[r + 2];
    float nm = __int_as_float(p.y);
    float f[4];
    unpack4(a0, f);
#pragma unroll
    for (int i = 0; i < 4; ++i) acc[i] += nm * f[i];
    unpack4(a1, f);
#pragma unroll
    for (int i = 0; i < 4; ++i) acc[4 + i] += nm * f[i];
    unpack4(a2, f);
#pragma unroll
    for (int i = 0; i < 4; ++i) acc[8 + i] += nm * f[i];
  }
  float z[12];
#pragma unroll
  for (int d = 0; d < C; ++d) z[d] = bs[d];
  z[11] = 0.f;
  const float2* X2v = reinterpret_cast<const float2*>(Xh);
  long own = (long)tid * 3;
#pragma unroll
  for (int q = 0; q < 3; ++q) {
    float xv[4], tv[4];
    unpack4(X2v[own + q], xv);
    unpack4(A2v[own + q], tv);
#pragma unroll
    for (int k = 0; k < 4; ++k) {
      int c = q * 4 + k;
      if (c == 11) continue;
      float xc = xv[k], tc = tv[k], ac = acc[c];
#pragma unroll
      for (int d = 0; d < C; ++d)
        z[d] += xc * wx[c * C + d] + tc * w1[c * C + d] + ac * w2[c * C + d];
    }
  }
  float2* o2 = reinterpret_cast<float2*>(P2l) + (long)tid * 3;
  o2[0] = pack4(z);
  o2[1] = pack4(z + 4);
  o2[2] = pack4(z + 8);
}

// ---------------- final: grid-stride; sums partial pairs while staging; z @ W[44,128] + bias ----
__global__ __launch_bounds__(256) void final_kernel(const __half* __restrict__ Pbase,
                                                    const float* __restrict__ W, const float* __restrict__ bias,
                                                    float* __restrict__ out) {
  __shared__ __half zsr[64][48];   // [row][H(24) T(24)]
  int tid = threadIdx.x;
  int c = tid & 127, h = tid >> 7;
  float wp[48];
#pragma unroll
  for (int off = 0; off < 48; ++off) {
    int half_ = off / 24, r_ = off - half_ * 24;
    int t = r_ / 12, c_ = r_ - t * 12;
    wp[off] = (c_ == 11) ? 0.f : W[(2 * (c_ + half_ * 11) + t) * 128 + c];
  }
  float bh = bias[c];
  for (int tile = blockIdx.x; tile < 7500; tile += gridDim.x) {
    long r0 = (long)tile * 64;
    __syncthreads();
#pragma unroll
    for (int it = 0; it < 2; ++it) {
      int item = it * 256 + tid;          // 384 items = 64 rows x 6 float4
      if (item < 384) {
        int row = item / 6, piece = item - row * 6;
        long r = r0 + row;
        int b = (int)(r / NN), n = (int)(r - (long)b * NN);
        int sp = (piece < 3) ? 0 : 2;
        int f4i = (piece < 3) ? piece : piece - 3;
        const float4* sA = reinterpret_cast<const float4*>(Pbase + (size_t)sp * T1SLOT);
        const float4* sB = reinterpret_cast<const float4*>(Pbase + (size_t)(sp + 1) * T1SLOT);
        long idx = (long)n * 48 + b * 3 + f4i;
        float fa[8], fb[8];
        unpack8(sA[idx], fa);
        unpack8(sB[idx], fb);
#pragma unroll
        for (int i = 0; i < 8; ++i) fa[i] += fb[i];
        *reinterpret_cast<float4*>(&zsr[row][(piece < 3 ? 0 : 24) + f4i * 8]) = pack8(fa);
      }
    }
    __syncthreads();
    int rbeg = h * 32;
#pragma unroll 2
    for (int row = rbeg; row < rbeg + 32; ++row) {
      const float4* zr4 = reinterpret_cast<const float4*>(&zsr[row][0]);
      float acc = bh;
#pragma unroll
      for (int q = 0; q < 6; ++q) {
        F4H8 u; u.v = zr4[q];
#pragma unroll
        for (int i = 0; i < 8; ++i)
          acc = fmaf(__half2float(u.h[i]), wp[q * 8 + i], acc);
      }
      out[(r0 + row) * 128 + c] = acc;
    }
  }
}

extern "C" void kernel_launch(void* const* d_in, const int* in_sizes, int n_in,
                              void* d_out, int out_size, void* d_ws, size_t ws_size,
                              hipStream_t stream) {
  const float* x    = (const float*)d_in[0];
  const int*   hg   = (const int*)d_in[1];
  const int*   tg   = (const int*)d_in[2];
  const float* t1w  = (const float*)d_in[3];
  const float* t1b  = (const float*)d_in[4];
  const float* h1W  = (const float*)d_in[5];
  const float* h1b  = (const float*)d_in[6];
  const float* g1W  = (const float*)d_in[7];
  const float* g1b  = (const float*)d_in[8];
  const float* a2w  = (const float*)d_in[9];
  const float* a2b  = (const float*)d_in[10];
  const float* t2w  = (const float*)d_in[11];
  const float* t2b  = (const float*)d_in[12];
  const float* h2W  = (const float*)d_in[13];
  const float* h2b  = (const float*)d_in[14];
  const float* g2W  = (const float*)d_in[15];
  const float* g2b  = (const float*)d_in[16];
  const float* outw = (const float*)d_in[17];
  const float* outb = (const float*)d_in[18];
  float* out = (float*)d_out;

  // workspace layout
  __half* T1h = (__half*)d_ws;                 // 4 slots x T1SLOT halfs (pull outputs)
  __half* Xh  = T1h + 4L * T1SLOT;             // X1 [N][64][8] -> X2n [N][32][12]
  __half* P   = Xh + T1SLOT;                   // 4 slots x T1SLOT halfs (cheb partials)
  int* csrBase  = (int*)(P + 4L * T1SLOT);     // 4 * CSR_STRIDE ints
  // CSR-build scratch aliased into P (dead before cheb1 writes P)
  int* degO     = (int*)P;                     // 4*NN
  int* degI     = degO + 4 * NN;               // 4*NN
  int* cursor   = degI + 4 * NN;               // 4*NN
  int* partials = cursor + 4 * NN;             // 4*NCH

  // --- build CSR (sorted by dst) + norms for all 4 edge lists, batched ---
  hipMemsetAsync(degO, 0, 8 * NN * sizeof(int), stream);
  count_all_kernel<<<(4 * EDGES + 255) / 256, 256, 0, stream>>>(hg, tg, degO, degI);
  scan1_kernel<<<4 * NCH, 256, 0, stream>>>(degI, csrBase, partials);
  scan2_kernel<<<1, 128, 0, stream>>>(partials);
  fixup_kernel<<<4 * NCH, 256, 0, stream>>>(csrBase, cursor, partials);
  fill_all_kernel<<<(4 * EDGES + 255) / 256, 256, 0, stream>>>(hg, tg, degO, degI, cursor, csrBase);

  // --- block1 ---
  glu1_kernel<<<NN * 64 / 256, 256, 0, stream>>>(x, t1w, t1b, Xh);
  pull1_kernel<<<4 * NN * 64 / 256, 256, 0, stream>>>(csrBase, Xh, T1h);
  for (int l = 0; l < 4; ++l) {
    const float* W1 = ((l < 2) ? h1W : g1W) + (size_t)(l & 1) * 3 * 64;
    const float* b1 = ((l < 2) ? h1b : g1b) + (size_t)(l & 1) * 8;
    cheb1_kernel<<<NN * 64 / 256, 256, 0, stream>>>(CSR_RP(csrBase, l), CSR_PK(csrBase, l),
                                                    Xh, T1h + (size_t)l * T1SLOT, W1, b1,
                                                    P + (size_t)l * T1SLOT);
  }

  // --- block2 ---
  glu2_kernel<<<NN * 32 / 256, 256, 0, stream>>>(P, t2w, t2b, a2w, a2b, Xh);
  pull2_kernel<<<4 * NN * 96 / 256, 256, 0, stream>>>(csrBase, Xh, T1h);
  for (int l = 0; l < 4; ++l) {
    const float* W2 = ((l < 2) ? h2W : g2W) + (size_t)(l & 1) * 3 * 121;
    const float* b2 = ((l < 2) ? h2b : g2b) + (size_t)(l & 1) * 11;
    cheb2_kernel<<<NN * 32 / 256, 256, 0, stream>>>(CSR_RP(csrBase, l), CSR_PK(csrBase, l),
                                                    Xh, T1h + (size_t)l * T1SLOT, W2, b2,
                                                    P + (size_t)l * T1SLOT);
  }

  // --- final linear ---
  final_kernel<<<1024, 256, 0, stream>>>(P, outw, outb, out);
}

// Round 11
// 896.162 us; speedup vs baseline: 1.4849x; 1.0691x over previous
//
#include <hip/hip_runtime.h>
#include <hip/hip_fp16.h>
#include <math.h>

#define EDGES 120000
#define NN    30000
#define NCH   118   // ceil(30000/256)
#define T1SLOT 15360000   // halfs per slot (NN*64*8)

__device__ __forceinline__ float sigmoidf_(float x) { return 1.f / (1.f + __expf(-x)); }

union F4H8 { float4 v; __half h[8]; };
union F2H4 { float2 v; __half h[4]; };

__device__ __forceinline__ void unpack8(float4 v, float* f) {
  F4H8 u; u.v = v;
#pragma unroll
  for (int i = 0; i < 8; ++i) f[i] = __half2float(u.h[i]);
}
__device__ __forceinline__ float4 pack8(const float* f) {
  F4H8 u;
#pragma unroll
  for (int i = 0; i < 8; ++i) u.h[i] = __float2half(f[i]);
  return u.v;
}
__device__ __forceinline__ void unpack4(float2 v, float* f) {
  F2H4 u; u.v = v;
#pragma unroll
  for (int i = 0; i < 4; ++i) f[i] = __half2float(u.h[i]);
}
__device__ __forceinline__ float2 pack4(const float* f) {
  F2H4 u;
#pragma unroll
  for (int i = 0; i < 4; ++i) u.h[i] = __float2half(f[i]);
  return u.v;
}

// CSR slot layout (ints): rowptr[30016] | pack int2[120000] (src, norm-bits)
#define CSR_STRIDE 270016
#define CSR_RP(base, l)   ((base) + (size_t)(l) * CSR_STRIDE)
#define CSR_PK(base, l)   ((const int2*)((base) + (size_t)(l) * CSR_STRIDE + 30016))
#define CSR_PKW(base, l)  ((int2*)((base) + (size_t)(l) * CSR_STRIDE + 30016))

// ---------------- CSR build ----------------
__global__ void count_all_kernel(const int* __restrict__ hg, const int* __restrict__ tg,
                                 int* __restrict__ degO, int* __restrict__ degI) {
  int tid = blockIdx.x * blockDim.x + threadIdx.x;
  if (tid >= 4 * EDGES) return;
  int l = tid / EDGES, j = tid - l * EDGES;
  const int* G = (l < 2) ? hg : tg;
  const int* src = G + (size_t)(l & 1) * 2 * EDGES;
  const int* dst = src + EDGES;
  atomicAdd(&degO[l * NN + src[j]], 1);
  atomicAdd(&degI[l * NN + dst[j]], 1);
}

__global__ __launch_bounds__(256) void scan1_kernel(const int* __restrict__ degI,
                                                    int* __restrict__ csrBase,
                                                    int* __restrict__ partials) {
  int l = blockIdx.x / NCH, ch = blockIdx.x - l * NCH;
  int tid = threadIdx.x;
  int i = ch * 256 + tid;
  __shared__ int buf[256];
  int v = (i < NN) ? degI[l * NN + i] : 0;
  buf[tid] = v;
  __syncthreads();
  for (int off = 1; off < 256; off <<= 1) {
    int t = (tid >= off) ? buf[tid - off] : 0;
    __syncthreads();
    buf[tid] += t;
    __syncthreads();
  }
  int* rp = CSR_RP(csrBase, l);
  if (i < NN) rp[i + 1] = buf[tid];
  if (tid == 255) partials[l * NCH + ch] = buf[255];
}

__global__ __launch_bounds__(128) void scan2_kernel(int* __restrict__ partials) {
  __shared__ int buf[128];
  int tid = threadIdx.x;
  for (int l = 0; l < 4; ++l) {
    int v = (tid < NCH) ? partials[l * NCH + tid] : 0;
    buf[tid] = v;
    __syncthreads();
    for (int off = 1; off < 128; off <<= 1) {
      int t = (tid >= off) ? buf[tid - off] : 0;
      __syncthreads();
      buf[tid] += t;
      __syncthreads();
    }
    if (tid < NCH) partials[l * NCH + tid] = buf[tid] - v;  // exclusive
    __syncthreads();
  }
}

__global__ __launch_bounds__(256) void fixup_kernel(int* __restrict__ csrBase,
                                                    int* __restrict__ cursor,
                                                    const int* __restrict__ partials) {
  int l = blockIdx.x / NCH, ch = blockIdx.x - l * NCH;
  int i = ch * 256 + threadIdx.x;
  int* rp = CSR_RP(csrBase, l);
  int off = partials[l * NCH + ch];
  if (i < NN) {
    int val = rp[i + 1] + off;
    rp[i + 1] = val;
    if (i + 1 < NN) cursor[l * NN + i + 1] = val;
  }
  if (i == 0) { rp[0] = 0; cursor[l * NN] = 0; }
}

__global__ void fill_all_kernel(const int* __restrict__ hg, const int* __restrict__ tg,
                                const int* __restrict__ degO, const int* __restrict__ degI,
                                int* __restrict__ cursor, int* __restrict__ csrBase) {
  int tid = blockIdx.x * blockDim.x + threadIdx.x;
  if (tid >= 4 * EDGES) return;
  int l = tid / EDGES, j = tid - l * EDGES;
  const int* G = (l < 2) ? hg : tg;
  const int* src = G + (size_t)(l & 1) * 2 * EDGES;
  const int* dst = src + EDGES;
  int s = src[j], d = dst[j];
  int doo = degO[l * NN + s]; if (doo < 1) doo = 1;
  int dii = degI[l * NN + d]; if (dii < 1) dii = 1;
  float nm = rsqrtf((float)doo) * rsqrtf((float)dii);
  int p = atomicAdd(&cursor[l * NN + d], 1);
  CSR_PKW(csrBase, l)[p] = make_int2(s, __float_as_int(nm));
}

// ---------------- block1 temporal GLU conv: x[B,N,6,1] -> X1h [N][64][8] fp16 ----------------
__global__ void glu1_kernel(const float* __restrict__ x, const float* __restrict__ w,
                            const float* __restrict__ b, __half* __restrict__ X1h) {
  int idx = blockIdx.x * blockDim.x + threadIdx.x;   // idx = n*64 + s, s = b*4 + t
  if (idx >= NN * 64) return;
  int n = idx >> 6, s = idx & 63;
  int bb = s >> 2, t = s & 3;
  const float* xb = x + ((long)bb * NN + n) * 6;
  float x0 = xb[t], x1 = xb[t + 1], x2 = xb[t + 2];
  float o[8];
#pragma unroll
  for (int c = 0; c < 8; ++c) {
    float p = w[c * 3 + 0] * x0 + w[c * 3 + 1] * x1 + w[c * 3 + 2] * x2 + b[c];
    float q = w[(c + 8) * 3 + 0] * x0 + w[(c + 8) * 3 + 1] * x1 + w[(c + 8) * 3 + 2] * x2 + b[c + 8];
    float al = (c == 0) ? x2 : 0.f;
    o[c] = (p + al) * sigmoidf_(q);
  }
  reinterpret_cast<float4*>(X1h)[idx] = pack8(o);
}

// ---------------- block1 pull (batched: all 4 lists gather the SHARED X1 buffer) ----------------
__global__ __launch_bounds__(256) void pull1_kernel(const int* __restrict__ csrBase,
                                                    const __half* __restrict__ Xh,
                                                    __half* __restrict__ T1hAll) {
  int gtid = blockIdx.x * 256 + threadIdx.x;
  int l = gtid / (NN * 64);
  int t = gtid - l * (NN * 64);
  int n = t >> 6, j = t & 63;
  const int* rp = CSR_RP(csrBase, l);
  const int2* pk = CSR_PK(csrBase, l);
  const float4* in4 = reinterpret_cast<const float4*>(Xh);
  float acc[8];
#pragma unroll
  for (int i = 0; i < 8; ++i) acc[i] = 0.f;
  int e = rp[n], end = rp[n + 1];
  for (; e + 4 <= end; e += 4) {
    int2 p0 = pk[e], p1 = pk[e + 1], p2 = pk[e + 2], p3 = pk[e + 3];
    float4 v0 = in4[(long)p0.x * 64 + j];
    float4 v1 = in4[(long)p1.x * 64 + j];
    float4 v2 = in4[(long)p2.x * 64 + j];
    float4 v3 = in4[(long)p3.x * 64 + j];
    float f[8];
    float n0 = __int_as_float(p0.y), n1 = __int_as_float(p1.y);
    float n2 = __int_as_float(p2.y), n3 = __int_as_float(p3.y);
    unpack8(v0, f);
#pragma unroll
    for (int i = 0; i < 8; ++i) acc[i] -= n0 * f[i];
    unpack8(v1, f);
#pragma unroll
    for (int i = 0; i < 8; ++i) acc[i] -= n1 * f[i];
    unpack8(v2, f);
#pragma unroll
    for (int i = 0; i < 8; ++i) acc[i] -= n2 * f[i];
    unpack8(v3, f);
#pragma unroll
    for (int i = 0; i < 8; ++i) acc[i] -= n3 * f[i];
  }
  for (; e < end; ++e) {
    int2 p = pk[e];
    float4 v = in4[(long)p.x * 64 + j];
    float nm = __int_as_float(p.y);
    float f[8];
    unpack8(v, f);
#pragma unroll
    for (int i = 0; i < 8; ++i) acc[i] -= nm * f[i];
  }
  reinterpret_cast<float4*>(T1hAll)[(size_t)l * (T1SLOT / 8) + t] = pack8(acc);
}

// ---------------- block1 Cheb: ONE list per launch, ADD folds etype pair into one buffer ----------
// Pl (=|+=) X*(W0-W2) + T1own*W1 + gather_l(T1[l])*(-2W2) + bias
__global__ __launch_bounds__(256) void cheb1_kernel(const int* __restrict__ rp, const int2* __restrict__ pk,
    const __half* __restrict__ Xh, const __half* __restrict__ T1l,
    const float* __restrict__ W, const float* __restrict__ bias,
    __half* __restrict__ Pl, int addFlag) {
  constexpr int C = 8, CC = 64;
  __shared__ float wx[CC], w1[CC], w2[CC], bs[C];
  for (int i = threadIdx.x; i < CC; i += 256) {
    float w0v = W[i], w1v = W[CC + i], w2v = W[2 * CC + i];
    wx[i] = w0v - w2v; w1[i] = w1v; w2[i] = -2.f * w2v;
  }
  if (threadIdx.x < C) bs[threadIdx.x] = bias[threadIdx.x];
  __syncthreads();
  int tid = blockIdx.x * 256 + threadIdx.x;
  int n = tid >> 6, s = tid & 63;
  const float4* T4 = reinterpret_cast<const float4*>(T1l);
  float acc[C];
#pragma unroll
  for (int c = 0; c < C; ++c) acc[c] = 0.f;
  int e = rp[n], end = rp[n + 1];
  for (; e + 4 <= end; e += 4) {
    int2 p0 = pk[e], p1 = pk[e + 1], p2 = pk[e + 2], p3 = pk[e + 3];
    float4 v0 = T4[(long)p0.x * 64 + s];
    float4 v1 = T4[(long)p1.x * 64 + s];
    float4 v2 = T4[(long)p2.x * 64 + s];
    float4 v3 = T4[(long)p3.x * 64 + s];
    float n0 = __int_as_float(p0.y), n1 = __int_as_float(p1.y);
    float n2 = __int_as_float(p2.y), n3 = __int_as_float(p3.y);
    float f[8];
    unpack8(v0, f);
#pragma unroll
    for (int c = 0; c < C; ++c) acc[c] += n0 * f[c];
    unpack8(v1, f);
#pragma unroll
    for (int c = 0; c < C; ++c) acc[c] += n1 * f[c];
    unpack8(v2, f);
#pragma unroll
    for (int c = 0; c < C; ++c) acc[c] += n2 * f[c];
    unpack8(v3, f);
#pragma unroll
    for (int c = 0; c < C; ++c) acc[c] += n3 * f[c];
  }
  for (; e < end; ++e) {
    int2 p = pk[e];
    float4 v = T4[(long)p.x * 64 + s];
    float nm = __int_as_float(p.y);
    float f[8];
    unpack8(v, f);
#pragma unroll
    for (int c = 0; c < C; ++c) acc[c] += nm * f[c];
  }
  float xv[C], tv[C];
  unpack8(reinterpret_cast<const float4*>(Xh)[tid], xv);
  unpack8(T4[tid], tv);
  float z[C];
#pragma unroll
  for (int d = 0; d < C; ++d) z[d] = bs[d];
#pragma unroll
  for (int c = 0; c < C; ++c) {
    float xc = xv[c], tc = tv[c], ac = acc[c];
#pragma unroll
    for (int d = 0; d < C; ++d)
      z[d] += xc * wx[c * C + d] + tc * w1[c * C + d] + ac * w2[c * C + d];
  }
  if (addFlag) {
    float fo[8];
    unpack8(reinterpret_cast<float4*>(Pl)[tid], fo);
#pragma unroll
    for (int d = 0; d < C; ++d) z[d] += fo[d];
  }
  reinterpret_cast<float4*>(Pl)[tid] = pack8(z);
}

// ---------------- block2 align(1x1)+GLU (round-6 form): H/T [N][64][8] -> X2nh [N][32][12] ----------
__global__ __launch_bounds__(256) void glu2_kernel(const __half* __restrict__ H, const __half* __restrict__ Tt,
                                                   const float* __restrict__ w2, const float* __restrict__ b2,
                                                   const float* __restrict__ aw, const float* __restrict__ ab,
                                                   __half* __restrict__ X2nh) {
  __shared__ float w2s[22 * 16 * 3], b2s[22], aws[11 * 16], abs_[11];
  for (int i = threadIdx.x; i < 22 * 16 * 3; i += 256) w2s[i] = w2[i];
  if (threadIdx.x < 22) b2s[threadIdx.x] = b2[threadIdx.x];
  for (int i = threadIdx.x; i < 11 * 16; i += 256) aws[i] = aw[i];
  if (threadIdx.x < 11) abs_[threadIdx.x] = ab[threadIdx.x];
  __syncthreads();
  int idx = blockIdx.x * 256 + threadIdx.x;   // idx = n*32 + s2, s2 = b*2 + t
  int n = idx >> 5, s = idx & 31;
  int bb = s >> 1, t = s & 1;
  long rbase = (long)n * 64 + bb * 4 + t;     // float4 row index (8 halfs per slice)
  const float4* H4 = reinterpret_cast<const float4*>(H) + rbase;
  const float4* T4 = reinterpret_cast<const float4*>(Tt) + rbase;
  float hv[24], tv[24];
  unpack8(H4[0], hv); unpack8(H4[1], hv + 8); unpack8(H4[2], hv + 16);
  unpack8(T4[0], tv); unpack8(T4[1], tv + 8); unpack8(T4[2], tv + 16);
  float o[12];
  o[11] = 0.f;
#pragma unroll
  for (int co = 0; co < 11; ++co) {
    float p = b2s[co], q = b2s[co + 11], a = abs_[co];
#pragma unroll
    for (int ci = 0; ci < 16; ++ci) {
      float v0 = (ci < 8) ? hv[ci] : tv[ci - 8];
      float v1 = (ci < 8) ? hv[8 + ci] : tv[ci];
      float v2 = (ci < 8) ? hv[16 + ci] : tv[8 + ci];
      p += w2s[(co * 16 + ci) * 3 + 0] * v0 + w2s[(co * 16 + ci) * 3 + 1] * v1 +
           w2s[(co * 16 + ci) * 3 + 2] * v2;
      q += w2s[((co + 11) * 16 + ci) * 3 + 0] * v0 + w2s[((co + 11) * 16 + ci) * 3 + 1] * v1 +
           w2s[((co + 11) * 16 + ci) * 3 + 2] * v2;
      a += aws[co * 16 + ci] * v2;
    }
    o[co] = (p + a) * sigmoidf_(q);
  }
  float2* o2 = reinterpret_cast<float2*>(X2nh) + (long)idx * 3;
  o2[0] = pack4(o);
  o2[1] = pack4(o + 4);
  o2[2] = pack4(o + 8);
}

// ---------------- block2 pull (batched: all 4 lists gather the SHARED X2nh buffer) ----------------
__global__ __launch_bounds__(256) void pull2_kernel(const int* __restrict__ csrBase,
                                                    const __half* __restrict__ Xh,
                                                    __half* __restrict__ T1hAll) {
  int gtid = blockIdx.x * 256 + threadIdx.x;
  int l = gtid / (NN * 96);
  int t = gtid - l * (NN * 96);
  int n = t / 96, j = t - n * 96;
  const int* rp = CSR_RP(csrBase, l);
  const int2* pk = CSR_PK(csrBase, l);
  const float2* in2 = reinterpret_cast<const float2*>(Xh);
  float acc[4];
#pragma unroll
  for (int i = 0; i < 4; ++i) acc[i] = 0.f;
  int e = rp[n], end = rp[n + 1];
  for (; e + 4 <= end; e += 4) {
    int2 p0 = pk[e], p1 = pk[e + 1], p2 = pk[e + 2], p3 = pk[e + 3];
    float2 v0 = in2[(long)p0.x * 96 + j];
    float2 v1 = in2[(long)p1.x * 96 + j];
    float2 v2 = in2[(long)p2.x * 96 + j];
    float2 v3 = in2[(long)p3.x * 96 + j];
    float f[4];
    float n0 = __int_as_float(p0.y), n1 = __int_as_float(p1.y);
    float n2 = __int_as_float(p2.y), n3 = __int_as_float(p3.y);
    unpack4(v0, f);
#pragma unroll
    for (int i = 0; i < 4; ++i) acc[i] -= n0 * f[i];
    unpack4(v1, f);
#pragma unroll
    for (int i = 0; i < 4; ++i) acc[i] -= n1 * f[i];
    unpack4(v2, f);
#pragma unroll
    for (int i = 0; i < 4; ++i) acc[i] -= n2 * f[i];
    unpack4(v3, f);
#pragma unroll
    for (int i = 0; i < 4; ++i) acc[i] -= n3 * f[i];
  }
  for (; e < end; ++e) {
    int2 p = pk[e];
    float2 v = in2[(long)p.x * 96 + j];
    float nm = __int_as_float(p.y);
    float f[4];
    unpack4(v, f);
#pragma unroll
    for (int i = 0; i < 4; ++i) acc[i] -= nm * f[i];
  }
  reinterpret_cast<float2*>(T1hAll)[(size_t)l * (T1SLOT / 4) + t] = pack4(acc);
}

// ---------------- block2 Cheb: ONE list per launch, ADD folds etype pair ----------------
__global__ __launch_bounds__(256) void cheb2_kernel(const int* __restrict__ rp, const int2* __restrict__ pk,
    const __half* __restrict__ Xh, const __half* __restrict__ T1l,
    const float* __restrict__ W, const float* __restrict__ bias,
    __half* __restrict__ P2l, int addFlag) {
  constexpr int C = 11, CC = 121;
  __shared__ float wx[CC], w1[CC], w2[CC], bs[C];
  for (int i = threadIdx.x; i < CC; i += 256) {
    float w0v = W[i], w1v = W[CC + i], w2v = W[2 * CC + i];
    wx[i] = w0v - w2v; w1[i] = w1v; w2[i] = -2.f * w2v;
  }
  if (threadIdx.x < C) bs[threadIdx.x] = bias[threadIdx.x];
  __syncthreads();
  int tid = blockIdx.x * 256 + threadIdx.x;
  int n = tid >> 5, s = tid & 31;
  int s3 = s * 3;
  const float2* A2v = reinterpret_cast<const float2*>(T1l);
  float acc[12];
#pragma unroll
  for (int c = 0; c < 12; ++c) acc[c] = 0.f;
  int e = rp[n], end = rp[n + 1];
  for (; e + 4 <= end; e += 4) {
    int2 p0 = pk[e], p1 = pk[e + 1], p2 = pk[e + 2], p3 = pk[e + 3];
    long r0 = (long)p0.x * 96 + s3, r1 = (long)p1.x * 96 + s3;
    long r2 = (long)p2.x * 96 + s3, r3 = (long)p3.x * 96 + s3;
    float2 a0 = A2v[r0], a1 = A2v[r0 + 1], a2 = A2v[r0 + 2];
    float2 b0 = A2v[r1], b1 = A2v[r1 + 1], b2 = A2v[r1 + 2];
    float2 c0 = A2v[r2], c1 = A2v[r2 + 1], c2 = A2v[r2 + 2];
    float2 d0 = A2v[r3], d1 = A2v[r3 + 1], d2 = A2v[r3 + 2];
    float n0 = __int_as_float(p0.y), n1 = __int_as_float(p1.y);
    float n2 = __int_as_float(p2.y), n3 = __int_as_float(p3.y);
    float f[4];
    unpack4(a0, f);
#pragma unroll
    for (int i = 0; i < 4; ++i) acc[i] += n0 * f[i];
    unpack4(a1, f);
#pragma unroll
    for (int i = 0; i < 4; ++i) acc[4 + i] += n0 * f[i];
    unpack4(a2, f);
#pragma unroll
    for (int i = 0; i < 4; ++i) acc[8 + i] += n0 * f[i];
    unpack4(b0, f);
#pragma unroll
    for (int i = 0; i < 4; ++i) acc[i] += n1 * f[i];
    unpack4(b1, f);
#pragma unroll
    for (int i = 0; i < 4; ++i) acc[4 + i] += n1 * f[i];
    unpack4(b2, f);
#pragma unroll
    for (int i = 0; i < 4; ++i) acc[8 + i] += n1 * f[i];
    unpack4(c0, f);
#pragma unroll
    for (int i = 0; i < 4; ++i) acc[i] += n2 * f[i];
    unpack4(c1, f);
#pragma unroll
    for (int i = 0; i < 4; ++i) acc[4 + i] += n2 * f[i];
    unpack4(c2, f);
#pragma unroll
    for (int i = 0; i < 4; ++i) acc[8 + i] += n2 * f[i];
    unpack4(d0, f);
#pragma unroll
    for (int i = 0; i < 4; ++i) acc[i] += n3 * f[i];
    unpack4(d1, f);
#pragma unroll
    for (int i = 0; i < 4; ++i) acc[4 + i] += n3 * f[i];
    unpack4(d2, f);
#pragma unroll
    for (int i = 0; i < 4; ++i) acc[8 + i] += n3 * f[i];
  }
  for (; e < end; ++e) {
    int2 p = pk[e];
    long r = (long)p.x * 96 + s3;
    float2 a0 = A2v[r], a1 = A2v[r + 1], a2 = A2v[r + 2];
    float nm = __int_as_float(p.y);
    float f[4];
    unpack4(a0, f);
#pragma unroll
    for (int i = 0; i < 4; ++i) acc[i] += nm * f[i];
    unpack4(a1, f);
#pragma unroll
    for (int i = 0; i < 4; ++i) acc[4 + i] += nm * f[i];
    unpack4(a2, f);
#pragma unroll
    for (int i = 0; i < 4; ++i) acc[8 + i] += nm * f[i];
  }
  float z[12];
#pragma unroll
  for (int d = 0; d < C; ++d) z[d] = bs[d];
  z[11] = 0.f;
  const float2* X2v = reinterpret_cast<const float2*>(Xh);
  long own = (long)tid * 3;
#pragma unroll
  for (int q = 0; q < 3; ++q) {
    float xv[4], tv[4];
    unpack4(X2v[own + q], xv);
    unpack4(A2v[own + q], tv);
#pragma unroll
    for (int k = 0; k < 4; ++k) {
      int c = q * 4 + k;
      if (c == 11) continue;
      float xc = xv[k], tc = tv[k], ac = acc[c];
#pragma unroll
      for (int d = 0; d < C; ++d)
        z[d] += xc * wx[c * C + d] + tc * w1[c * C + d] + ac * w2[c * C + d];
    }
  }
  float2* o2 = reinterpret_cast<float2*>(P2l) + (long)tid * 3;
  if (addFlag) {
    float fo[4];
    unpack4(o2[0], fo);
#pragma unroll
    for (int i = 0; i < 4; ++i) z[i] += fo[i];
    unpack4(o2[1], fo);
#pragma unroll
    for (int i = 0; i < 4; ++i) z[4 + i] += fo[i];
    unpack4(o2[2], fo);
#pragma unroll
    for (int i = 0; i < 4; ++i) z[8 + i] += fo[i];
  }
  o2[0] = pack4(z);
  o2[1] = pack4(z + 4);
  o2[2] = pack4(z + 8);
}

// ---------------- final: grid-stride; fp16->fp32 conversion ONCE during LDS staging ----------------
__global__ __launch_bounds__(256) void final_kernel(const __half* __restrict__ H2, const __half* __restrict__ T2b,
                                                    const float* __restrict__ W, const float* __restrict__ bias,
                                                    float* __restrict__ out) {
  __shared__ float zsr[64][48];   // 12 KB: z rows pre-converted to fp32
  int tid = threadIdx.x;
  int c = tid & 127, h = tid >> 7;
  float wp[48];
#pragma unroll
  for (int off = 0; off < 48; ++off) {
    int half_ = off / 24, r_ = off - half_ * 24;
    int t = r_ / 12, c_ = r_ - t * 12;
    wp[off] = (c_ == 11) ? 0.f : W[(2 * (c_ + half_ * 11) + t) * 128 + c];
  }
  float bh = bias[c];
  for (int tile = blockIdx.x; tile < 7500; tile += gridDim.x) {
    long r0 = (long)tile * 64;
    __syncthreads();
#pragma unroll
    for (int it = 0; it < 2; ++it) {
      int item = it * 256 + tid;          // 384 items = 64 rows x 6 float4 (8 halfs each)
      if (item < 384) {
        int row = item / 6, piece = item - row * 6;
        long r = r0 + row;
        int b = (int)(r / NN), n = (int)(r - (long)b * NN);
        const float4* srcb = reinterpret_cast<const float4*>(piece < 3 ? H2 : T2b);
        int f4i = (piece < 3) ? piece : piece - 3;
        float4 v = srcb[(long)n * 48 + b * 3 + f4i];
        float f[8];
        unpack8(v, f);
        float4* d = reinterpret_cast<float4*>(&zsr[row][(piece < 3 ? 0 : 24) + f4i * 8]);
        d[0] = make_float4(f[0], f[1], f[2], f[3]);
        d[1] = make_float4(f[4], f[5], f[6], f[7]);
      }
    }
    __syncthreads();
    int rbeg = h * 32;
#pragma unroll 2
    for (int row = rbeg; row < rbeg + 32; ++row) {
      const float4* zr4 = reinterpret_cast<const float4*>(&zsr[row][0]);
      float acc = bh;
#pragma unroll
      for (int q = 0; q < 12; ++q) {
        float4 zv = zr4[q];
        acc = fmaf(zv.x, wp[4 * q + 0], acc);
        acc = fmaf(zv.y, wp[4 * q + 1], acc);
        acc = fmaf(zv.z, wp[4 * q + 2], acc);
        acc = fmaf(zv.w, wp[4 * q + 3], acc);
      }
      out[(r0 + row) * 128 + c] = acc;
    }
  }
}

extern "C" void kernel_launch(void* const* d_in, const int* in_sizes, int n_in,
                              void* d_out, int out_size, void* d_ws, size_t ws_size,
                              hipStream_t stream) {
  const float* x    = (const float*)d_in[0];
  const int*   hg   = (const int*)d_in[1];
  const int*   tg   = (const int*)d_in[2];
  const float* t1w  = (const float*)d_in[3];
  const float* t1b  = (const float*)d_in[4];
  const float* h1W  = (const float*)d_in[5];
  const float* h1b  = (const float*)d_in[6];
  const float* g1W  = (const float*)d_in[7];
  const float* g1b  = (const float*)d_in[8];
  const float* a2w  = (const float*)d_in[9];
  const float* a2b  = (const float*)d_in[10];
  const float* t2w  = (const float*)d_in[11];
  const float* t2b  = (const float*)d_in[12];
  const float* h2W  = (const float*)d_in[13];
  const float* h2b  = (const float*)d_in[14];
  const float* g2W  = (const float*)d_in[15];
  const float* g2b  = (const float*)d_in[16];
  const float* outw = (const float*)d_in[17];
  const float* outb = (const float*)d_in[18];
  float* out = (float*)d_out;

  // workspace layout
  __half* T1h = (__half*)d_ws;                 // 4 slots x T1SLOT halfs (pull outputs)
  __half* Xh  = T1h + 4L * T1SLOT;             // X1 [N][64][8] -> X2n [N][32][12]
  __half* PH  = Xh + T1SLOT;                   // block1 H combined -> block2 Cfh
  __half* PT  = PH + T1SLOT;                   // block1 T combined -> block2 Dfh
  int* csrBase  = (int*)(PT + T1SLOT);         // 4 * CSR_STRIDE ints
  // CSR-build scratch aliased into PH (dead before cheb1 writes PH)
  int* degO     = (int*)PH;                    // 4*NN
  int* degI     = degO + 4 * NN;               // 4*NN
  int* cursor   = degI + 4 * NN;               // 4*NN
  int* partials = cursor + 4 * NN;             // 4*NCH

  // --- build CSR (sorted by dst) + norms for all 4 edge lists, batched ---
  hipMemsetAsync(degO, 0, 8 * NN * sizeof(int), stream);
  count_all_kernel<<<(4 * EDGES + 255) / 256, 256, 0, stream>>>(hg, tg, degO, degI);
  scan1_kernel<<<4 * NCH, 256, 0, stream>>>(degI, csrBase, partials);
  scan2_kernel<<<1, 128, 0, stream>>>(partials);
  fixup_kernel<<<4 * NCH, 256, 0, stream>>>(csrBase, cursor, partials);
  fill_all_kernel<<<(4 * EDGES + 255) / 256, 256, 0, stream>>>(hg, tg, degO, degI, cursor, csrBase);

  // --- block1 ---
  glu1_kernel<<<NN * 64 / 256, 256, 0, stream>>>(x, t1w, t1b, Xh);
  pull1_kernel<<<4 * NN * 64 / 256, 256, 0, stream>>>(csrBase, Xh, T1h);
  for (int l = 0; l < 4; ++l) {
    const float* W1 = ((l < 2) ? h1W : g1W) + (size_t)(l & 1) * 3 * 64;
    const float* b1 = ((l < 2) ? h1b : g1b) + (size_t)(l & 1) * 8;
    __half* dst = (l < 2) ? PH : PT;
    cheb1_kernel<<<NN * 64 / 256, 256, 0, stream>>>(CSR_RP(csrBase, l), CSR_PK(csrBase, l),
                                                    Xh, T1h + (size_t)l * T1SLOT, W1, b1,
                                                    dst, l & 1);
  }

  // --- block2 ---
  glu2_kernel<<<NN * 32 / 256, 256, 0, stream>>>(PH, PT, t2w, t2b, a2w, a2b, Xh);
  pull2_kernel<<<4 * NN * 96 / 256, 256, 0, stream>>>(csrBase, Xh, T1h);
  for (int l = 0; l < 4; ++l) {
    const float* W2 = ((l < 2) ? h2W : g2W) + (size_t)(l & 1) * 3 * 121;
    const float* b2 = ((l < 2) ? h2b : g2b) + (size_t)(l & 1) * 11;
    __half* dst = (l < 2) ? PH : PT;
    cheb2_kernel<<<NN * 32 / 256, 256, 0, stream>>>(CSR_RP(csrBase, l), CSR_PK(csrBase, l),
                                                    Xh, T1h + (size_t)l * T1SLOT, W2, b2,
                                                    dst, l & 1);
  }

  // --- final linear ---
  final_kernel<<<1024, 256, 0, stream>>>(PH, PT, outw, outb, out);
}